// Round 9
// baseline (4095.935 us; speedup 1.0000x reference)
//
#include <hip/hip_runtime.h>

#define HID 512
#define NB  256
#define TT  256
#define DIN 64
#define HBUF 131072                  // shorts per h half-panel (hi or lo)
#define SLOT_SH (2 * HBUF)           // hi+lo slot, shorts (512 KB)
#define NSLOT 8                      // rotation depth; fence every NSLOT iters

typedef __attribute__((ext_vector_type(8))) short short8;
typedef __attribute__((ext_vector_type(4))) float f32x4;

__device__ __forceinline__ unsigned short f2bf(float f) {
    unsigned int u = __float_as_uint(f);
    u += 0x7FFF + ((u >> 16) & 1);
    return (unsigned short)(u >> 16);
}
__device__ __forceinline__ float bf2f(unsigned short h) {
    return __uint_as_float(((unsigned int)h) << 16);
}

// ---- LLC-coherent (cross-XCD) 4B access, explicit sc0/sc1 cache bits ----
__device__ __forceinline__ void st_u32_llc(unsigned* p, unsigned v) {
    asm volatile("global_store_dword %0, %1, off sc0 sc1" :: "v"(p), "v"(v) : "memory");
}
__device__ __forceinline__ unsigned ld_u32_llc(const unsigned* p) {
    unsigned v;
    asm volatile("global_load_dword %0, %1, off sc0 sc1\n\ts_waitcnt vmcnt(0)"
                 : "=v"(v) : "v"(p) : "memory");
    return v;
}

#define MFMA3(acc, ah, al, bh, bl)                                          \
    acc = __builtin_amdgcn_mfma_f32_16x16x32_bf16(ah, bh, acc, 0, 0, 0);    \
    acc = __builtin_amdgcn_mfma_f32_16x16x32_bf16(ah, bl, acc, 0, 0, 0);    \
    acc = __builtin_amdgcn_mfma_f32_16x16x32_bf16(al, bh, acc, 0, 0, 0);

// LDS layout (shorts): sW0 h/l: 18*512 each; sW1 h/l: 32*512 each; then sG floats
#define SW0_N 9216
#define SW1_N 16384
#define LDS_BYTES ((SW0_N * 2 + SW1_N * 2) * 2 + 128 * 17 * 4)

// ---- per-group barrier: vmcnt drain -> LLC flag store -> LLC poll (128 flags);
// ---- window fence (1/NSLOT iters) in a NON-polling wave concurrent with poll.
__device__ __forceinline__ void group_barrier(unsigned* gfg, int it, int jb, bool fence) {
    asm volatile("s_waitcnt vmcnt(0)" ::: "memory");   // h stores complete at LLC
    __syncthreads();
    if (threadIdx.x == 0) st_u32_llc(gfg + jb, (unsigned)(it + 1));
    if (fence && threadIdx.x >= 448)                   // wave 7: L1+L2 invalidate
        __builtin_amdgcn_fence(__ATOMIC_ACQUIRE, "agent");
    if (threadIdx.x < 128) {                           // waves 0-1 poll own group
        unsigned* p = gfg + threadIdx.x;
        while ((int)ld_u32_llc(p) < it + 1) __builtin_amdgcn_s_sleep(2);
    }
    __syncthreads();
}

// packed 2-lane h store: lanes (l, l+1) hold adjacent j; even lane stores u32
__device__ __forceinline__ void store_h_pair(unsigned short* buf, size_t hoff,
                                             unsigned short v, int l) {
    unsigned int hv = (unsigned int)v;
    unsigned int up = __shfl_down(hv, 1);
    if ((l & 1) == 0)
        st_u32_llc((unsigned*)(buf + hoff), hv | (up << 16));
}

__global__ __launch_bounds__(512) void lstm_persistent(
    const float* __restrict__ x,
    const float* __restrict__ Wih0, const float* __restrict__ Whh0,
    const float* __restrict__ bih0, const float* __restrict__ bhh0,
    const float* __restrict__ Wih1, const float* __restrict__ Whh1,
    const float* __restrict__ bih1, const float* __restrict__ bhh1,
    const float* __restrict__ headw, const float* __restrict__ headb,
    unsigned short* h0base, unsigned short* h1base,
    unsigned* gf, float* __restrict__ out)
{
    extern __shared__ unsigned short lds[];
    unsigned short* sW0h = lds;
    unsigned short* sW0l = sW0h + SW0_N;
    unsigned short* sW1h = sW0l + SW0_N;
    unsigned short* sW1l = sW1h + SW1_N;
    float* sG = (float*)(sW1l + SW1_N);          // [128][17]

    const int tid = threadIdx.x;
    const int l   = tid & 63;
    const int w   = tid >> 6;         // wave 0..7
    const int bid = blockIdx.x;
    const int g   = bid & 1;          // batch group
    const int jb  = bid >> 1;         // j-block 0..127 (hidden units jb*4..jb*4+3)

    unsigned* gfg = gf + g * 128;

    // ---- weight preload: fp32 -> hi/lo bf16 fragments in LDS ----
    const int r  = l & 15;
    const int ks = (l >> 4) * 8;
    const int n  = (r >> 2) * HID + jb * 4 + (r & 3);
    {
        for (int kt = w; kt < 18; kt += 8) {
            const float* src = (kt < 2) ? (Wih0 + (size_t)n * DIN + kt * 32 + ks)
                                        : (Whh0 + (size_t)n * HID + (kt - 2) * 32 + ks);
            float v[8];
            *(float4*)&v[0] = *(const float4*)src;
            *(float4*)&v[4] = *(const float4*)(src + 4);
            union { unsigned short u[8]; uint4 q; } ph, pl;
            #pragma unroll
            for (int e = 0; e < 8; ++e) {
                unsigned short h = f2bf(v[e]);
                ph.u[e] = h; pl.u[e] = f2bf(v[e] - bf2f(h));
            }
            *(uint4*)&sW0h[(kt * 64 + l) * 8] = ph.q;
            *(uint4*)&sW0l[(kt * 64 + l) * 8] = pl.q;
        }
        for (int kt = w; kt < 32; kt += 8) {
            const float* src = (kt < 16) ? (Wih1 + (size_t)n * HID + kt * 32 + ks)
                                         : (Whh1 + (size_t)n * HID + (kt - 16) * 32 + ks);
            float v[8];
            *(float4*)&v[0] = *(const float4*)src;
            *(float4*)&v[4] = *(const float4*)(src + 4);
            union { unsigned short u[8]; uint4 q; } ph, pl;
            #pragma unroll
            for (int e = 0; e < 8; ++e) {
                unsigned short h = f2bf(v[e]);
                ph.u[e] = h; pl.u[e] = f2bf(v[e] - bf2f(h));
            }
            *(uint4*)&sW1h[(kt * 64 + l) * 8] = ph.q;
            *(uint4*)&sW1l[(kt * 64 + l) * 8] = pl.q;
        }
    }

    float bias0[4], bias1[4];
    #pragma unroll
    for (int gi = 0; gi < 4; ++gi) {
        const int nn = gi * HID + jb * 4 + (l & 3);
        bias0[gi] = bih0[nn] + bhh0[nn];
        bias1[gi] = bih1[nn] + bhh1[nn];
    }
    float c0 = 0.f, c1 = 0.f;

    const int jj      = l & 3;
    const int b_local = 16 * w + (l >> 2);
    const int b_glob  = g * 128 + b_local;
    const int j_glob  = jb * 4 + jj;
    const size_t hoff = ((((size_t)(b_glob >> 4)) * 16 + (j_glob >> 5)) * 64
                         + ((b_glob & 15) | (((j_glob >> 3) & 3) << 4))) * 8 + (j_glob & 7);
    const int bt = g * 8 + w;        // this wave's global batch tile

    // x prefetch registers
    const int xrow = g * 128 + w * 16 + (l & 15);
    float xv0[8], xv1[8];
    {
        const float* s0 = x + ((size_t)xrow * TT + 0) * DIN + ks;
        *(float4*)&xv0[0] = *(const float4*)s0;
        *(float4*)&xv0[4] = *(const float4*)(s0 + 4);
        *(float4*)&xv1[0] = *(const float4*)(s0 + 32);
        *(float4*)&xv1[4] = *(const float4*)(s0 + 36);
    }

    __syncthreads();                 // weights ready

    for (int it = 0; it <= TT; ++it) {
        // slot map: h0[t] -> slot t&7 ; h1[t] -> slot t&7
        const unsigned short* h0c_h = h0base + (size_t)((it + 7) & 7) * SLOT_SH;  // h0[it-1]
        const unsigned short* h0c_l = h0c_h + HBUF;
        unsigned short* h0n_h = h0base + (size_t)(it & 7) * SLOT_SH;              // h0[it]
        unsigned short* h0n_l = h0n_h + HBUF;
        const unsigned short* h1c_h = h1base + (size_t)((it + 6) & 7) * SLOT_SH;  // h1[it-2]
        const unsigned short* h1c_l = h1c_h + HBUF;
        unsigned short* h1n_h = h1base + (size_t)((it + 7) & 7) * SLOT_SH;        // h1[it-1]
        unsigned short* h1n_l = h1n_h + HBUF;

        f32x4 acc0[2] = {{0.f,0.f,0.f,0.f},{0.f,0.f,0.f,0.f}};
        f32x4 acc1[2] = {{0.f,0.f,0.f,0.f},{0.f,0.f,0.f,0.f}};

        // ---- phase A (fused): each h0[it-1] fragment loaded ONCE feeds
        // ----   layer0 (W0hh -> acc0) AND layer1 ys0-part (W1ih -> acc1)
        #pragma unroll
        for (int kt = 0; kt < 16; ++kt) {
            const size_t o = (((size_t)bt * 16 + kt) * 64 + l) * 8;
            short8 ah = *(const short8*)&h0c_h[o];
            short8 al = *(const short8*)&h0c_l[o];
            short8 b0h = *(const short8*)&sW0h[((kt + 2) * 64 + l) * 8];
            short8 b0l = *(const short8*)&sW0l[((kt + 2) * 64 + l) * 8];
            MFMA3(acc0[kt & 1], ah, al, b0h, b0l);
            short8 b1h = *(const short8*)&sW1h[(kt * 64 + l) * 8];
            short8 b1l = *(const short8*)&sW1l[(kt * 64 + l) * 8];
            MFMA3(acc1[kt & 1], ah, al, b1h, b1l);
        }
        // ---- layer0 x part (prefetched registers)
        if (it < TT) {
            #pragma unroll
            for (int kt = 0; kt < 2; ++kt) {
                const float* v = kt ? xv1 : xv0;
                union { unsigned short u[8]; short8 s; } ah, al;
                #pragma unroll
                for (int e = 0; e < 8; ++e) {
                    unsigned short h = f2bf(v[e]);
                    ah.u[e] = h; al.u[e] = f2bf(v[e] - bf2f(h));
                }
                short8 bh = *(const short8*)&sW0h[(kt * 64 + l) * 8];
                short8 bl = *(const short8*)&sW0l[(kt * 64 + l) * 8];
                MFMA3(acc0[kt & 1], ah.s, al.s, bh, bl);
            }
        }
        // prefetch x[it+1] (hides under phase C)
        if (it + 1 < TT) {
            const float* s0 = x + ((size_t)xrow * TT + (it + 1)) * DIN + ks;
            *(float4*)&xv0[0] = *(const float4*)s0;
            *(float4*)&xv0[4] = *(const float4*)(s0 + 4);
            *(float4*)&xv1[0] = *(const float4*)(s0 + 32);
            *(float4*)&xv1[4] = *(const float4*)(s0 + 36);
        }
        // ---- phase C: layer1 h1[it-2] part
        #pragma unroll
        for (int kt = 0; kt < 16; ++kt) {
            const size_t o = (((size_t)bt * 16 + kt) * 64 + l) * 8;
            short8 ch = *(const short8*)&h1c_h[o];
            short8 cl = *(const short8*)&h1c_l[o];
            short8 bh = *(const short8*)&sW1h[((kt + 16) * 64 + l) * 8];
            short8 bl = *(const short8*)&sW1l[((kt + 16) * 64 + l) * 8];
            MFMA3(acc1[kt & 1], ch, cl, bh, bl);
        }

        // ---- epilogue layer0
        if (it < TT) {
            #pragma unroll
            for (int q = 0; q < 4; ++q)
                sG[(16 * w + (l >> 4) * 4 + q) * 17 + (l & 15)] = acc0[0][q] + acc0[1][q];
            __syncthreads();
            {
                const float gi_ = sG[b_local * 17 + jj]      + bias0[0];
                const float gf_ = sG[b_local * 17 + 4 + jj]  + bias0[1];
                const float gg_ = sG[b_local * 17 + 8 + jj]  + bias0[2];
                const float go_ = sG[b_local * 17 + 12 + jj] + bias0[3];
                const float iG = 1.f / (1.f + expf(-gi_));
                const float fG = 1.f / (1.f + expf(-gf_));
                const float gT = tanhf(gg_);
                const float oG = 1.f / (1.f + expf(-go_));
                c0 = fmaf(fG, c0, iG * gT);
                const float h = oG * tanhf(c0);
                const unsigned short hh = f2bf(h);
                store_h_pair(h0n_h, hoff, hh, l);
                store_h_pair(h0n_l, hoff, f2bf(h - bf2f(hh)), l);
            }
            __syncthreads();
        }
        // ---- epilogue layer1
        if (it > 0) {
            #pragma unroll
            for (int q = 0; q < 4; ++q)
                sG[(16 * w + (l >> 4) * 4 + q) * 17 + (l & 15)] = acc1[0][q] + acc1[1][q];
            __syncthreads();
            {
                const float gi_ = sG[b_local * 17 + jj]      + bias1[0];
                const float gf_ = sG[b_local * 17 + 4 + jj]  + bias1[1];
                const float gg_ = sG[b_local * 17 + 8 + jj]  + bias1[2];
                const float go_ = sG[b_local * 17 + 12 + jj] + bias1[3];
                const float iG = 1.f / (1.f + expf(-gi_));
                const float fG = 1.f / (1.f + expf(-gf_));
                const float gT = tanhf(gg_);
                const float oG = 1.f / (1.f + expf(-go_));
                c1 = fmaf(fG, c1, iG * gT);
                const float h = oG * tanhf(c1);
                const unsigned short hh = f2bf(h);
                store_h_pair(h1n_h, hoff, hh, l);
                store_h_pair(h1n_l, hoff, f2bf(h - bf2f(hh)), l);
            }
            __syncthreads();
        }

        group_barrier(gfg, it, jb, (it & 7) == 7);
    }

    // ---- head: out[b] = h1[TT-1] . w + b (slot 7; fenced at it=255, fresh LLC pull)
    if (jb == 0) {
        const unsigned short* h1h = h1base + (size_t)((TT + 7) & 7) * SLOT_SH;
        const unsigned short* h1l = h1h + HBUF;
        const int bl_ = tid >> 2;
        const int qd  = tid & 3;
        const int b   = g * 128 + bl_;
        const int btw = b >> 4;
        float s = 0.f;
        #pragma unroll
        for (int jt = qd * 4; jt < qd * 4 + 4; ++jt) {
            #pragma unroll
            for (int q2 = 0; q2 < 4; ++q2) {
                const size_t off = (((size_t)btw * 16 + jt) * 64 + ((b & 15) | (q2 << 4))) * 8;
                short8 vh = *(const short8*)&h1h[off];
                short8 vl = *(const short8*)&h1l[off];
                const int j0 = jt * 32 + q2 * 8;
                #pragma unroll
                for (int e = 0; e < 8; ++e)
                    s += (bf2f((unsigned short)vh[e]) + bf2f((unsigned short)vl[e])) * headw[j0 + e];
            }
        }
        s += __shfl_down(s, 2, 4);
        s += __shfl_down(s, 1, 4);
        if (qd == 0) out[b] = s + headb[0];
    }
}

extern "C" void kernel_launch(void* const* d_in, const int* in_sizes, int n_in,
                              void* d_out, int out_size, void* d_ws, size_t ws_size,
                              hipStream_t stream) {
    const float* x      = (const float*)d_in[0];
    const float* W_ih0  = (const float*)d_in[1];
    const float* W_hh0  = (const float*)d_in[2];
    const float* b_ih0  = (const float*)d_in[3];
    const float* b_hh0  = (const float*)d_in[4];
    const float* W_ih1  = (const float*)d_in[5];
    const float* W_hh1  = (const float*)d_in[6];
    const float* b_ih1  = (const float*)d_in[7];
    const float* b_hh1  = (const float*)d_in[8];
    const float* head_w = (const float*)d_in[9];
    const float* head_b = (const float*)d_in[10];
    float* out = (float*)d_out;

    // ws layout: [flags 1KB][pad to 1MB][h0: 8 slots x 512KB][h1: 8 slots x 512KB]
    const size_t SLOT_BYTES = (size_t)SLOT_SH * 2;          // 512 KB
    unsigned* gf = (unsigned*)d_ws;
    unsigned short* h0base = (unsigned short*)((char*)d_ws + (1 << 20));
    unsigned short* h1base = (unsigned short*)((char*)d_ws + (1 << 20) + NSLOT * SLOT_BYTES);

    // zero: flags + the t=-1 slots (slot 7 of each chain)
    hipMemsetAsync(d_ws, 0, 4096, stream);
    hipMemsetAsync((char*)h0base + 7 * SLOT_BYTES, 0, SLOT_BYTES, stream);
    hipMemsetAsync((char*)h1base + 7 * SLOT_BYTES, 0, SLOT_BYTES, stream);

    hipFuncSetAttribute((const void*)lstm_persistent,
                        hipFuncAttributeMaxDynamicSharedMemorySize, LDS_BYTES);
    lstm_persistent<<<dim3(256), dim3(512), LDS_BYTES, stream>>>(
        x, W_ih0, W_hh0, b_ih0, b_hh0, W_ih1, W_hh1, b_ih1, b_hh1,
        head_w, head_b, h0base, h1base, gf, out);
}

// Round 11
// 2939.692 us; speedup vs baseline: 1.3933x; 1.3933x over previous
//
#include <hip/hip_runtime.h>

#define HID 512
#define NB  256
#define TT  256
#define DIN 64
#define HBUF 131072                  // shorts per h half-panel (hi or lo)
#define SLOT_SH (2 * HBUF)           // hi+lo slot, shorts (512 KB)
#define NSLOT 8                      // rotation depth; fence every NSLOT iters

typedef __attribute__((ext_vector_type(8))) short short8;
typedef __attribute__((ext_vector_type(4))) float f32x4;

__device__ __forceinline__ unsigned short f2bf(float f) {
    unsigned int u = __float_as_uint(f);
    u += 0x7FFF + ((u >> 16) & 1);
    return (unsigned short)(u >> 16);
}
__device__ __forceinline__ float bf2f(unsigned short h) {
    return __uint_as_float(((unsigned int)h) << 16);
}

// ---- LLC-coherent (cross-XCD) 4B access, explicit sc0/sc1 cache bits ----
__device__ __forceinline__ void st_u32_llc(unsigned* p, unsigned v) {
    asm volatile("global_store_dword %0, %1, off sc0 sc1" :: "v"(p), "v"(v) : "memory");
}
__device__ __forceinline__ unsigned ld_u32_llc(const unsigned* p) {
    unsigned v;
    asm volatile("global_load_dword %0, %1, off sc0 sc1\n\ts_waitcnt vmcnt(0)"
                 : "=v"(v) : "v"(p) : "memory");
    return v;
}

#define MFMA3(acc, ah, al, bh, bl)                                          \
    acc = __builtin_amdgcn_mfma_f32_16x16x32_bf16(ah, bh, acc, 0, 0, 0);    \
    acc = __builtin_amdgcn_mfma_f32_16x16x32_bf16(ah, bl, acc, 0, 0, 0);    \
    acc = __builtin_amdgcn_mfma_f32_16x16x32_bf16(al, bh, acc, 0, 0, 0);

// LDS layout (shorts): sW0 h/l: 18*512 each; sW1 h/l: 32*512 each; then sG floats
#define SW0_N 9216
#define SW1_N 16384
#define LDS_BYTES ((SW0_N * 2 + SW1_N * 2) * 2 + 128 * 17 * 4)

// packed 2-lane h store: lanes (l, l+1) hold adjacent j; even lane stores u32
__device__ __forceinline__ void store_h_pair(unsigned short* buf, size_t hoff,
                                             unsigned short v, int l) {
    unsigned int hv = (unsigned int)v;
    unsigned int up = __shfl_down(hv, 1);
    if ((l & 1) == 0)
        st_u32_llc((unsigned*)(buf + hoff), hv | (up << 16));
}

// wait: 128 lanes poll one flag each (LLC loads, no cache pollution), then barrier
__device__ __forceinline__ void flag_wait(unsigned* fset, int target) {
    if (threadIdx.x < 128) {
        unsigned* p = fset + threadIdx.x;
        while ((int)ld_u32_llc(p) < target) __builtin_amdgcn_s_sleep(2);
    }
    __syncthreads();
}

__global__ __launch_bounds__(512, 2) void lstm_persistent(
    const float* __restrict__ x,
    const float* __restrict__ Wih0, const float* __restrict__ Whh0,
    const float* __restrict__ bih0, const float* __restrict__ bhh0,
    const float* __restrict__ Wih1, const float* __restrict__ Whh1,
    const float* __restrict__ bih1, const float* __restrict__ bhh1,
    const float* __restrict__ headw, const float* __restrict__ headb,
    unsigned short* h0base, unsigned short* h1base,
    unsigned* gf, float* __restrict__ out)
{
    extern __shared__ unsigned short lds[];
    unsigned short* sW0h = lds;
    unsigned short* sW0l = sW0h + SW0_N;
    unsigned short* sW1h = sW0l + SW0_N;
    unsigned short* sW1l = sW1h + SW1_N;
    float* sG = (float*)(sW1l + SW1_N);          // [128][17]

    const int tid = threadIdx.x;
    const int l   = tid & 63;
    const int w   = tid >> 6;         // wave 0..7
    const int bid = blockIdx.x;
    const int g   = bid & 1;          // batch group
    const int jb  = bid >> 1;         // j-block 0..127 (hidden units jb*4..jb*4+3)

    unsigned* f0g = gf + g * 128;            // layer0-done flags (this group)
    unsigned* f1g = gf + 256 + g * 128;      // layer1-done flags (this group)

    // ---- weight preload: fp32 -> hi/lo bf16 fragments in LDS ----
    const int r  = l & 15;
    const int ks = (l >> 4) * 8;
    const int n  = (r >> 2) * HID + jb * 4 + (r & 3);
    {
        for (int kt = w; kt < 18; kt += 8) {
            const float* src = (kt < 2) ? (Wih0 + (size_t)n * DIN + kt * 32 + ks)
                                        : (Whh0 + (size_t)n * HID + (kt - 2) * 32 + ks);
            float v[8];
            *(float4*)&v[0] = *(const float4*)src;
            *(float4*)&v[4] = *(const float4*)(src + 4);
            union { unsigned short u[8]; uint4 q; } ph, pl;
            #pragma unroll
            for (int e = 0; e < 8; ++e) {
                unsigned short h = f2bf(v[e]);
                ph.u[e] = h; pl.u[e] = f2bf(v[e] - bf2f(h));
            }
            *(uint4*)&sW0h[(kt * 64 + l) * 8] = ph.q;
            *(uint4*)&sW0l[(kt * 64 + l) * 8] = pl.q;
        }
        for (int kt = w; kt < 32; kt += 8) {
            const float* src = (kt < 16) ? (Wih1 + (size_t)n * HID + kt * 32 + ks)
                                         : (Whh1 + (size_t)n * HID + (kt - 16) * 32 + ks);
            float v[8];
            *(float4*)&v[0] = *(const float4*)src;
            *(float4*)&v[4] = *(const float4*)(src + 4);
            union { unsigned short u[8]; uint4 q; } ph, pl;
            #pragma unroll
            for (int e = 0; e < 8; ++e) {
                unsigned short h = f2bf(v[e]);
                ph.u[e] = h; pl.u[e] = f2bf(v[e] - bf2f(h));
            }
            *(uint4*)&sW1h[(kt * 64 + l) * 8] = ph.q;
            *(uint4*)&sW1l[(kt * 64 + l) * 8] = pl.q;
        }
    }

    float bias0[4], bias1[4];
    #pragma unroll
    for (int gi = 0; gi < 4; ++gi) {
        const int nn = gi * HID + jb * 4 + (l & 3);
        bias0[gi] = bih0[nn] + bhh0[nn];
        bias1[gi] = bih1[nn] + bhh1[nn];
    }
    float c0 = 0.f, c1 = 0.f;

    const int jj      = l & 3;
    const int b_local = 16 * w + (l >> 2);
    const int b_glob  = g * 128 + b_local;
    const int j_glob  = jb * 4 + jj;
    const size_t hoff = ((((size_t)(b_glob >> 4)) * 16 + (j_glob >> 5)) * 64
                         + ((b_glob & 15) | (((j_glob >> 3) & 3) << 4))) * 8 + (j_glob & 7);
    const int bt = g * 8 + w;        // this wave's global batch tile

    // x prefetch registers
    const int xrow = g * 128 + w * 16 + (l & 15);
    float xv0[8], xv1[8];
    {
        const float* s0 = x + ((size_t)xrow * TT + 0) * DIN + ks;
        *(float4*)&xv0[0] = *(const float4*)s0;
        *(float4*)&xv0[4] = *(const float4*)(s0 + 4);
        *(float4*)&xv1[0] = *(const float4*)(s0 + 32);
        *(float4*)&xv1[4] = *(const float4*)(s0 + 36);
    }

    __syncthreads();                 // weights ready

    for (int it = 0; it <= TT; ++it) {
        // ---- wait 1: layer0 of it-1 done everywhere (signaled MID-iteration -> fast)
        flag_wait(f0g, it);

        // slot map: h0[t] -> slot t&7 ; h1[t] -> slot t&7
        const unsigned short* h0c_h = h0base + (size_t)((it + 7) & 7) * SLOT_SH;  // h0[it-1]
        const unsigned short* h0c_l = h0c_h + HBUF;
        unsigned short* h0n_h = h0base + (size_t)(it & 7) * SLOT_SH;              // h0[it]
        unsigned short* h0n_l = h0n_h + HBUF;
        const unsigned short* h1c_h = h1base + (size_t)((it + 6) & 7) * SLOT_SH;  // h1[it-2]
        const unsigned short* h1c_l = h1c_h + HBUF;
        unsigned short* h1n_h = h1base + (size_t)((it + 7) & 7) * SLOT_SH;        // h1[it-1]
        unsigned short* h1n_l = h1n_h + HBUF;

        f32x4 acc0[2] = {{0.f,0.f,0.f,0.f},{0.f,0.f,0.f,0.f}};
        f32x4 acc1[2] = {{0.f,0.f,0.f,0.f},{0.f,0.f,0.f,0.f}};

        // ---- hoisted h0[it-1] A-fragments: 32 b128 loads batched (MLP),
        // ---- used by layer0 (W0hh) AND layer1 ys0-part (W1ih)
        short8 fAh[16], fAl[16];
        #pragma unroll
        for (int kt = 0; kt < 16; ++kt) {
            const size_t o = (((size_t)bt * 16 + kt) * 64 + l) * 8;
            fAh[kt] = *(const short8*)&h0c_h[o];
            fAl[kt] = *(const short8*)&h0c_l[o];
        }

        // ================= layer 0, t = it =================
        if (it < TT) {
            #pragma unroll
            for (int kt = 0; kt < 2; ++kt) {
                const float* v = kt ? xv1 : xv0;
                union { unsigned short u[8]; short8 s; } ah, al;
                #pragma unroll
                for (int e = 0; e < 8; ++e) {
                    unsigned short h = f2bf(v[e]);
                    ah.u[e] = h; al.u[e] = f2bf(v[e] - bf2f(h));
                }
                short8 bh = *(const short8*)&sW0h[(kt * 64 + l) * 8];
                short8 bl = *(const short8*)&sW0l[(kt * 64 + l) * 8];
                MFMA3(acc0[kt & 1], ah.s, al.s, bh, bl);
            }
            #pragma unroll
            for (int kt = 0; kt < 16; ++kt) {
                short8 bh = *(const short8*)&sW0h[((kt + 2) * 64 + l) * 8];
                short8 bl = *(const short8*)&sW0l[((kt + 2) * 64 + l) * 8];
                MFMA3(acc0[kt & 1], fAh[kt], fAl[kt], bh, bl);
            }
            #pragma unroll
            for (int q = 0; q < 4; ++q)
                sG[(16 * w + (l >> 4) * 4 + q) * 17 + (l & 15)] = acc0[0][q] + acc0[1][q];
            __syncthreads();
            {
                const float gi_ = sG[b_local * 17 + jj]      + bias0[0];
                const float gf_ = sG[b_local * 17 + 4 + jj]  + bias0[1];
                const float gg_ = sG[b_local * 17 + 8 + jj]  + bias0[2];
                const float go_ = sG[b_local * 17 + 12 + jj] + bias0[3];
                const float iG = 1.f / (1.f + expf(-gi_));
                const float fG = 1.f / (1.f + expf(-gf_));
                const float gT = tanhf(gg_);
                const float oG = 1.f / (1.f + expf(-go_));
                c0 = fmaf(fG, c0, iG * gT);
                const float h = oG * tanhf(c0);
                const unsigned short hh = f2bf(h);
                store_h_pair(h0n_h, hoff, hh, l);
                store_h_pair(h0n_l, hoff, f2bf(h - bf2f(hh)), l);
            }
            // ---- EARLY layer0-done signal: unblocks next iteration's wait-1
            asm volatile("s_waitcnt vmcnt(0)" ::: "memory");
            __syncthreads();
            if (tid == 0) st_u32_llc(f0g + jb, (unsigned)(it + 1));
        }

        // prefetch x[it+1]
        if (it + 1 < TT) {
            const float* s0 = x + ((size_t)xrow * TT + (it + 1)) * DIN + ks;
            *(float4*)&xv0[0] = *(const float4*)s0;
            *(float4*)&xv0[4] = *(const float4*)(s0 + 4);
            *(float4*)&xv1[0] = *(const float4*)(s0 + 32);
            *(float4*)&xv1[4] = *(const float4*)(s0 + 36);
        }

        // ---- wait 2: layer1 of it-1 done everywhere (covers h1[it-2] writes).
        // Signaled at END of it-1 -> by now ~a full layer0 old -> usually fast.
        flag_wait(f1g, it);

        // ================= layer 1, t = it-1 =================
        if (it > 0) {
            // ys0 part: REUSE carried fragments (no global re-read)
            #pragma unroll
            for (int kt = 0; kt < 16; ++kt) {
                short8 bh = *(const short8*)&sW1h[(kt * 64 + l) * 8];
                short8 bl = *(const short8*)&sW1l[(kt * 64 + l) * 8];
                MFMA3(acc1[kt & 1], fAh[kt], fAl[kt], bh, bl);
            }
            #pragma unroll
            for (int kt = 0; kt < 16; ++kt) {
                const size_t o = (((size_t)bt * 16 + kt) * 64 + l) * 8;
                short8 ch = *(const short8*)&h1c_h[o];
                short8 cl = *(const short8*)&h1c_l[o];
                short8 bh = *(const short8*)&sW1h[((kt + 16) * 64 + l) * 8];
                short8 bl = *(const short8*)&sW1l[((kt + 16) * 64 + l) * 8];
                MFMA3(acc1[kt & 1], ch, cl, bh, bl);
            }
            #pragma unroll
            for (int q = 0; q < 4; ++q)
                sG[(16 * w + (l >> 4) * 4 + q) * 17 + (l & 15)] = acc1[0][q] + acc1[1][q];
            __syncthreads();
            {
                const float gi_ = sG[b_local * 17 + jj]      + bias1[0];
                const float gf_ = sG[b_local * 17 + 4 + jj]  + bias1[1];
                const float gg_ = sG[b_local * 17 + 8 + jj]  + bias1[2];
                const float go_ = sG[b_local * 17 + 12 + jj] + bias1[3];
                const float iG = 1.f / (1.f + expf(-gi_));
                const float fG = 1.f / (1.f + expf(-gf_));
                const float gT = tanhf(gg_);
                const float oG = 1.f / (1.f + expf(-go_));
                c1 = fmaf(fG, c1, iG * gT);
                const float h = oG * tanhf(c1);
                const unsigned short hh = f2bf(h);
                store_h_pair(h1n_h, hoff, hh, l);
                store_h_pair(h1n_l, hoff, f2bf(h - bf2f(hh)), l);
            }
        }
        // ---- layer1-done signal + windowed fence (1/NSLOT iters, non-polling wave)
        asm volatile("s_waitcnt vmcnt(0)" ::: "memory");
        __syncthreads();
        if (tid == 0) st_u32_llc(f1g + jb, (unsigned)(it + 1));
        if ((it & 7) == 7 && tid >= 448)
            __builtin_amdgcn_fence(__ATOMIC_ACQUIRE, "agent");
    }

    // ---- head: out[b] = h1[TT-1] . w + b (slot 7; all layer1 done first)
    if (jb == 0) {
        if (tid < 128) {
            unsigned* p = f1g + tid;
            while ((int)ld_u32_llc(p) < TT + 1) __builtin_amdgcn_s_sleep(2);
        }
        __syncthreads();
        const unsigned short* h1h = h1base + (size_t)((TT + 7) & 7) * SLOT_SH;
        const unsigned short* h1l = h1h + HBUF;
        const int bl_ = tid >> 2;
        const int qd  = tid & 3;
        const int b   = g * 128 + bl_;
        const int btw = b >> 4;
        float s = 0.f;
        #pragma unroll
        for (int jt = qd * 4; jt < qd * 4 + 4; ++jt) {
            #pragma unroll
            for (int q2 = 0; q2 < 4; ++q2) {
                const size_t off = (((size_t)btw * 16 + jt) * 64 + ((b & 15) | (q2 << 4))) * 8;
                short8 vh = *(const short8*)&h1h[off];
                short8 vl = *(const short8*)&h1l[off];
                const int j0 = jt * 32 + q2 * 8;
                #pragma unroll
                for (int e = 0; e < 8; ++e)
                    s += (bf2f((unsigned short)vh[e]) + bf2f((unsigned short)vl[e])) * headw[j0 + e];
            }
        }
        s += __shfl_down(s, 2, 4);
        s += __shfl_down(s, 1, 4);
        if (qd == 0) out[b] = s + headb[0];
    }
}

extern "C" void kernel_launch(void* const* d_in, const int* in_sizes, int n_in,
                              void* d_out, int out_size, void* d_ws, size_t ws_size,
                              hipStream_t stream) {
    const float* x      = (const float*)d_in[0];
    const float* W_ih0  = (const float*)d_in[1];
    const float* W_hh0  = (const float*)d_in[2];
    const float* b_ih0  = (const float*)d_in[3];
    const float* b_hh0  = (const float*)d_in[4];
    const float* W_ih1  = (const float*)d_in[5];
    const float* W_hh1  = (const float*)d_in[6];
    const float* b_ih1  = (const float*)d_in[7];
    const float* b_hh1  = (const float*)d_in[8];
    const float* head_w = (const float*)d_in[9];
    const float* head_b = (const float*)d_in[10];
    float* out = (float*)d_out;

    // ws layout: [flags 4KB (f0 g0,g1 | f1 g0,g1)][pad to 1MB][h0: 8x512KB][h1: 8x512KB]
    const size_t SLOT_BYTES = (size_t)SLOT_SH * 2;          // 512 KB
    unsigned* gf = (unsigned*)d_ws;
    unsigned short* h0base = (unsigned short*)((char*)d_ws + (1 << 20));
    unsigned short* h1base = (unsigned short*)((char*)d_ws + (1 << 20) + NSLOT * SLOT_BYTES);

    // zero: flags + the t=-1 slots (slot 7 of each chain)
    hipMemsetAsync(d_ws, 0, 4096, stream);
    hipMemsetAsync((char*)h0base + 7 * SLOT_BYTES, 0, SLOT_BYTES, stream);
    hipMemsetAsync((char*)h1base + 7 * SLOT_BYTES, 0, SLOT_BYTES, stream);

    hipFuncSetAttribute((const void*)lstm_persistent,
                        hipFuncAttributeMaxDynamicSharedMemorySize, LDS_BYTES);
    lstm_persistent<<<dim3(256), dim3(512), LDS_BYTES, stream>>>(
        x, W_ih0, W_hh0, b_ih0, b_hh0, W_ih1, W_hh1, b_ih1, b_hh1,
        head_w, head_b, h0base, h1base, gf, out);
}

// Round 12
// 2132.570 us; speedup vs baseline: 1.9207x; 1.3785x over previous
//
#include <hip/hip_runtime.h>

#define HID 512
#define NB  256
#define TT  256
#define DIN 64
#define HBUF 131072                  // shorts per h panel (bf16 hi only)
#define SLOT_SH HBUF                 // slot = one panel (256 KB)
#define NSLOT 8                      // rotation depth; fence every NSLOT iters

typedef __attribute__((ext_vector_type(8))) short short8;
typedef __attribute__((ext_vector_type(4))) float f32x4;

__device__ __forceinline__ unsigned short f2bf(float f) {
    unsigned int u = __float_as_uint(f);
    u += 0x7FFF + ((u >> 16) & 1);
    return (unsigned short)(u >> 16);
}
__device__ __forceinline__ float bf2f(unsigned short h) {
    return __uint_as_float(((unsigned int)h) << 16);
}

// ---- LLC-coherent (cross-XCD) 4B access, explicit sc0/sc1 cache bits ----
__device__ __forceinline__ void st_u32_llc(unsigned* p, unsigned v) {
    asm volatile("global_store_dword %0, %1, off sc0 sc1" :: "v"(p), "v"(v) : "memory");
}
__device__ __forceinline__ unsigned ld_u32_llc(const unsigned* p) {
    unsigned v;
    asm volatile("global_load_dword %0, %1, off sc0 sc1\n\ts_waitcnt vmcnt(0)"
                 : "=v"(v) : "v"(p) : "memory");
    return v;
}

// h-A operand is single bf16: 2-term split (A.Bh + A.Bl)
#define MFMA2(acc, a, bh, bl)                                               \
    acc = __builtin_amdgcn_mfma_f32_16x16x32_bf16(a, bh, acc, 0, 0, 0);     \
    acc = __builtin_amdgcn_mfma_f32_16x16x32_bf16(a, bl, acc, 0, 0, 0);
// x-A operand keeps hi/lo: 3-term split
#define MFMA3(acc, ah, al, bh, bl)                                          \
    acc = __builtin_amdgcn_mfma_f32_16x16x32_bf16(ah, bh, acc, 0, 0, 0);    \
    acc = __builtin_amdgcn_mfma_f32_16x16x32_bf16(ah, bl, acc, 0, 0, 0);    \
    acc = __builtin_amdgcn_mfma_f32_16x16x32_bf16(al, bh, acc, 0, 0, 0);

// LDS layout (shorts): sW0 h/l: 18*512 each; sW1 h/l: 32*512 each; then sG floats
#define SW0_N 9216
#define SW1_N 16384
#define LDS_BYTES ((SW0_N * 2 + SW1_N * 2) * 2 + 128 * 17 * 4)

// packed 2-lane h store: lanes (l, l+1) hold adjacent j; even lane stores u32
__device__ __forceinline__ void store_h_pair(unsigned short* buf, size_t hoff,
                                             unsigned short v, int l) {
    unsigned int hv = (unsigned int)v;
    unsigned int up = __shfl_down(hv, 1);
    if ((l & 1) == 0)
        st_u32_llc((unsigned*)(buf + hoff), hv | (up << 16));
}

// wait: 128 lanes poll one flag each (LLC loads, no cache pollution), then barrier
__device__ __forceinline__ void flag_wait(unsigned* fset, int target) {
    if (threadIdx.x < 128) {
        unsigned* p = fset + threadIdx.x;
        while ((int)ld_u32_llc(p) < target) __builtin_amdgcn_s_sleep(2);
    }
    __syncthreads();
}

__global__ __launch_bounds__(512, 2) void lstm_persistent(
    const float* __restrict__ x,
    const float* __restrict__ Wih0, const float* __restrict__ Whh0,
    const float* __restrict__ bih0, const float* __restrict__ bhh0,
    const float* __restrict__ Wih1, const float* __restrict__ Whh1,
    const float* __restrict__ bih1, const float* __restrict__ bhh1,
    const float* __restrict__ headw, const float* __restrict__ headb,
    unsigned short* h0base, unsigned short* h1base,
    unsigned* gf, float* __restrict__ out)
{
    extern __shared__ unsigned short lds[];
    unsigned short* sW0h = lds;
    unsigned short* sW0l = sW0h + SW0_N;
    unsigned short* sW1h = sW0l + SW0_N;
    unsigned short* sW1l = sW1h + SW1_N;
    float* sG = (float*)(sW1l + SW1_N);          // [128][17]

    const int tid = threadIdx.x;
    const int l   = tid & 63;
    const int w   = tid >> 6;         // wave 0..7
    const int bid = blockIdx.x;
    const int g   = bid & 1;          // batch group
    const int jb  = bid >> 1;         // j-block 0..127 (hidden units jb*4..jb*4+3)

    unsigned* f0g = gf + g * 128;            // layer0-done flags (this group)
    unsigned* f1g = gf + 256 + g * 128;      // layer1-done flags (this group)

    // ---- weight preload: fp32 -> hi/lo bf16 fragments in LDS ----
    const int r  = l & 15;
    const int ks = (l >> 4) * 8;
    const int n  = (r >> 2) * HID + jb * 4 + (r & 3);
    {
        for (int kt = w; kt < 18; kt += 8) {
            const float* src = (kt < 2) ? (Wih0 + (size_t)n * DIN + kt * 32 + ks)
                                        : (Whh0 + (size_t)n * HID + (kt - 2) * 32 + ks);
            float v[8];
            *(float4*)&v[0] = *(const float4*)src;
            *(float4*)&v[4] = *(const float4*)(src + 4);
            union { unsigned short u[8]; uint4 q; } ph, pl;
            #pragma unroll
            for (int e = 0; e < 8; ++e) {
                unsigned short h = f2bf(v[e]);
                ph.u[e] = h; pl.u[e] = f2bf(v[e] - bf2f(h));
            }
            *(uint4*)&sW0h[(kt * 64 + l) * 8] = ph.q;
            *(uint4*)&sW0l[(kt * 64 + l) * 8] = pl.q;
        }
        for (int kt = w; kt < 32; kt += 8) {
            const float* src = (kt < 16) ? (Wih1 + (size_t)n * HID + kt * 32 + ks)
                                         : (Whh1 + (size_t)n * HID + (kt - 16) * 32 + ks);
            float v[8];
            *(float4*)&v[0] = *(const float4*)src;
            *(float4*)&v[4] = *(const float4*)(src + 4);
            union { unsigned short u[8]; uint4 q; } ph, pl;
            #pragma unroll
            for (int e = 0; e < 8; ++e) {
                unsigned short h = f2bf(v[e]);
                ph.u[e] = h; pl.u[e] = f2bf(v[e] - bf2f(h));
            }
            *(uint4*)&sW1h[(kt * 64 + l) * 8] = ph.q;
            *(uint4*)&sW1l[(kt * 64 + l) * 8] = pl.q;
        }
    }

    float bias0[4], bias1[4];
    #pragma unroll
    for (int gi = 0; gi < 4; ++gi) {
        const int nn = gi * HID + jb * 4 + (l & 3);
        bias0[gi] = bih0[nn] + bhh0[nn];
        bias1[gi] = bih1[nn] + bhh1[nn];
    }
    float c0 = 0.f, c1 = 0.f;

    const int jj      = l & 3;
    const int b_local = 16 * w + (l >> 2);
    const int b_glob  = g * 128 + b_local;
    const int j_glob  = jb * 4 + jj;
    const size_t hoff = ((((size_t)(b_glob >> 4)) * 16 + (j_glob >> 5)) * 64
                         + ((b_glob & 15) | (((j_glob >> 3) & 3) << 4))) * 8 + (j_glob & 7);
    const int bt = g * 8 + w;        // this wave's global batch tile

    // x prefetch registers
    const int xrow = g * 128 + w * 16 + (l & 15);
    float xv0[8], xv1[8];
    {
        const float* s0 = x + ((size_t)xrow * TT + 0) * DIN + ks;
        *(float4*)&xv0[0] = *(const float4*)s0;
        *(float4*)&xv0[4] = *(const float4*)(s0 + 4);
        *(float4*)&xv1[0] = *(const float4*)(s0 + 32);
        *(float4*)&xv1[4] = *(const float4*)(s0 + 36);
    }

    __syncthreads();                 // weights ready

    for (int it = 0; it <= TT; ++it) {
        // ---- wait 1: layer0 of it-1 done everywhere (signaled MID-iteration -> fast)
        flag_wait(f0g, it);

        // slot map: h0[t] -> slot t&7 ; h1[t] -> slot t&7
        const unsigned short* h0c = h0base + (size_t)((it + 7) & 7) * SLOT_SH;  // h0[it-1]
        unsigned short* h0n       = h0base + (size_t)(it & 7) * SLOT_SH;        // h0[it]
        const unsigned short* h1c = h1base + (size_t)((it + 6) & 7) * SLOT_SH;  // h1[it-2]
        unsigned short* h1n       = h1base + (size_t)((it + 7) & 7) * SLOT_SH;  // h1[it-1]

        f32x4 acc0[2] = {{0.f,0.f,0.f,0.f},{0.f,0.f,0.f,0.f}};
        f32x4 acc1[2] = {{0.f,0.f,0.f,0.f},{0.f,0.f,0.f,0.f}};

        // ---- hoisted h0[it-1] A-fragments (bf16): 16 b128 loads batched (MLP),
        // ---- used by layer0 (W0hh) AND layer1 ys0-part (W1ih)
        short8 fAh[16];
        #pragma unroll
        for (int kt = 0; kt < 16; ++kt) {
            const size_t o = (((size_t)bt * 16 + kt) * 64 + l) * 8;
            fAh[kt] = *(const short8*)&h0c[o];
        }

        // ================= layer 0, t = it =================
        if (it < TT) {
            #pragma unroll
            for (int kt = 0; kt < 2; ++kt) {
                const float* v = kt ? xv1 : xv0;
                union { unsigned short u[8]; short8 s; } ah, al;
                #pragma unroll
                for (int e = 0; e < 8; ++e) {
                    unsigned short h = f2bf(v[e]);
                    ah.u[e] = h; al.u[e] = f2bf(v[e] - bf2f(h));
                }
                short8 bh = *(const short8*)&sW0h[(kt * 64 + l) * 8];
                short8 bl = *(const short8*)&sW0l[(kt * 64 + l) * 8];
                MFMA3(acc0[kt & 1], ah.s, al.s, bh, bl);
            }
            #pragma unroll
            for (int kt = 0; kt < 16; ++kt) {
                short8 bh = *(const short8*)&sW0h[((kt + 2) * 64 + l) * 8];
                short8 bl = *(const short8*)&sW0l[((kt + 2) * 64 + l) * 8];
                MFMA2(acc0[kt & 1], fAh[kt], bh, bl);
            }
            #pragma unroll
            for (int q = 0; q < 4; ++q)
                sG[(16 * w + (l >> 4) * 4 + q) * 17 + (l & 15)] = acc0[0][q] + acc0[1][q];
            __syncthreads();
            {
                const float gi_ = sG[b_local * 17 + jj]      + bias0[0];
                const float gf_ = sG[b_local * 17 + 4 + jj]  + bias0[1];
                const float gg_ = sG[b_local * 17 + 8 + jj]  + bias0[2];
                const float go_ = sG[b_local * 17 + 12 + jj] + bias0[3];
                const float iG = 1.f / (1.f + expf(-gi_));
                const float fG = 1.f / (1.f + expf(-gf_));
                const float gT = tanhf(gg_);
                const float oG = 1.f / (1.f + expf(-go_));
                c0 = fmaf(fG, c0, iG * gT);
                const float h = oG * tanhf(c0);
                store_h_pair(h0n, hoff, f2bf(h), l);
            }
            // ---- EARLY layer0-done signal: unblocks next iteration's wait-1
            asm volatile("s_waitcnt vmcnt(0)" ::: "memory");
            __syncthreads();
            if (tid == 0) st_u32_llc(f0g + jb, (unsigned)(it + 1));
        }

        // prefetch x[it+1]
        if (it + 1 < TT) {
            const float* s0 = x + ((size_t)xrow * TT + (it + 1)) * DIN + ks;
            *(float4*)&xv0[0] = *(const float4*)s0;
            *(float4*)&xv0[4] = *(const float4*)(s0 + 4);
            *(float4*)&xv1[0] = *(const float4*)(s0 + 32);
            *(float4*)&xv1[4] = *(const float4*)(s0 + 36);
        }

        // ---- wait 2: layer1 of it-1 done everywhere (covers h1[it-2] writes)
        flag_wait(f1g, it);

        // ================= layer 1, t = it-1 =================
        if (it > 0) {
            // ys0 part: REUSE carried fragments (no global re-read)
            #pragma unroll
            for (int kt = 0; kt < 16; ++kt) {
                short8 bh = *(const short8*)&sW1h[(kt * 64 + l) * 8];
                short8 bl = *(const short8*)&sW1l[(kt * 64 + l) * 8];
                MFMA2(acc1[kt & 1], fAh[kt], bh, bl);
            }
            // h1[it-2] part: batched fragment loads (MLP), then MFMAs
            short8 fCh[16];
            #pragma unroll
            for (int kt = 0; kt < 16; ++kt) {
                const size_t o = (((size_t)bt * 16 + kt) * 64 + l) * 8;
                fCh[kt] = *(const short8*)&h1c[o];
            }
            #pragma unroll
            for (int kt = 0; kt < 16; ++kt) {
                short8 bh = *(const short8*)&sW1h[((kt + 16) * 64 + l) * 8];
                short8 bl = *(const short8*)&sW1l[((kt + 16) * 64 + l) * 8];
                MFMA2(acc1[kt & 1], fCh[kt], bh, bl);
            }
            #pragma unroll
            for (int q = 0; q < 4; ++q)
                sG[(16 * w + (l >> 4) * 4 + q) * 17 + (l & 15)] = acc1[0][q] + acc1[1][q];
            __syncthreads();
            {
                const float gi_ = sG[b_local * 17 + jj]      + bias1[0];
                const float gf_ = sG[b_local * 17 + 4 + jj]  + bias1[1];
                const float gg_ = sG[b_local * 17 + 8 + jj]  + bias1[2];
                const float go_ = sG[b_local * 17 + 12 + jj] + bias1[3];
                const float iG = 1.f / (1.f + expf(-gi_));
                const float fG = 1.f / (1.f + expf(-gf_));
                const float gT = tanhf(gg_);
                const float oG = 1.f / (1.f + expf(-go_));
                c1 = fmaf(fG, c1, iG * gT);
                const float h = oG * tanhf(c1);
                store_h_pair(h1n, hoff, f2bf(h), l);
            }
        }
        // ---- layer1-done signal + windowed fence (1/NSLOT iters, non-polling wave)
        asm volatile("s_waitcnt vmcnt(0)" ::: "memory");
        __syncthreads();
        if (tid == 0) st_u32_llc(f1g + jb, (unsigned)(it + 1));
        if ((it & 7) == 7 && tid >= 448)
            __builtin_amdgcn_fence(__ATOMIC_ACQUIRE, "agent");
    }

    // ---- head: out[b] = h1[TT-1] . w + b (slot 7; all layer1 done first)
    if (jb == 0) {
        if (tid < 128) {
            unsigned* p = f1g + tid;
            while ((int)ld_u32_llc(p) < TT + 1) __builtin_amdgcn_s_sleep(2);
        }
        __syncthreads();
        const unsigned short* h1h = h1base + (size_t)((TT + 7) & 7) * SLOT_SH;
        const int bl_ = tid >> 2;
        const int qd  = tid & 3;
        const int b   = g * 128 + bl_;
        const int btw = b >> 4;
        float s = 0.f;
        #pragma unroll
        for (int jt = qd * 4; jt < qd * 4 + 4; ++jt) {
            #pragma unroll
            for (int q2 = 0; q2 < 4; ++q2) {
                const size_t off = (((size_t)btw * 16 + jt) * 64 + ((b & 15) | (q2 << 4))) * 8;
                short8 vh = *(const short8*)&h1h[off];
                const int j0 = jt * 32 + q2 * 8;
                #pragma unroll
                for (int e = 0; e < 8; ++e)
                    s += bf2f((unsigned short)vh[e]) * headw[j0 + e];
            }
        }
        s += __shfl_down(s, 2, 4);
        s += __shfl_down(s, 1, 4);
        if (qd == 0) out[b] = s + headb[0];
    }
}

extern "C" void kernel_launch(void* const* d_in, const int* in_sizes, int n_in,
                              void* d_out, int out_size, void* d_ws, size_t ws_size,
                              hipStream_t stream) {
    const float* x      = (const float*)d_in[0];
    const float* W_ih0  = (const float*)d_in[1];
    const float* W_hh0  = (const float*)d_in[2];
    const float* b_ih0  = (const float*)d_in[3];
    const float* b_hh0  = (const float*)d_in[4];
    const float* W_ih1  = (const float*)d_in[5];
    const float* W_hh1  = (const float*)d_in[6];
    const float* b_ih1  = (const float*)d_in[7];
    const float* b_hh1  = (const float*)d_in[8];
    const float* head_w = (const float*)d_in[9];
    const float* head_b = (const float*)d_in[10];
    float* out = (float*)d_out;

    // ws layout: [flags 4KB (f0 g0,g1 | f1 g0,g1)][pad to 1MB][h0: 8x256KB][h1: 8x256KB]
    const size_t SLOT_BYTES = (size_t)SLOT_SH * 2;          // 256 KB
    unsigned* gf = (unsigned*)d_ws;
    unsigned short* h0base = (unsigned short*)((char*)d_ws + (1 << 20));
    unsigned short* h1base = (unsigned short*)((char*)d_ws + (1 << 20) + NSLOT * SLOT_BYTES);

    // zero: flags + the t=-1 slots (slot 7 of each chain)
    hipMemsetAsync(d_ws, 0, 4096, stream);
    hipMemsetAsync((char*)h0base + 7 * SLOT_BYTES, 0, SLOT_BYTES, stream);
    hipMemsetAsync((char*)h1base + 7 * SLOT_BYTES, 0, SLOT_BYTES, stream);

    hipFuncSetAttribute((const void*)lstm_persistent,
                        hipFuncAttributeMaxDynamicSharedMemorySize, LDS_BYTES);
    lstm_persistent<<<dim3(256), dim3(512), LDS_BYTES, stream>>>(
        x, W_ih0, W_hh0, b_ih0, b_hh0, W_ih1, W_hh1, b_ih1, b_hh1,
        head_w, head_b, h0base, h1base, gf, out);
}